// Round 5
// baseline (2674.061 us; speedup 1.0000x reference)
//
#include <hip/hip_runtime.h>

#define N_S 400000
#define N_F 128
#define N_K 512
#define ITERS 10

typedef __attribute__((ext_vector_type(8))) short short8;
typedef __attribute__((ext_vector_type(4))) float floatx4;

__device__ inline unsigned short f2bf(float f) {
    unsigned int u = __float_as_uint(f);
    unsigned int r = (u + 0x7FFFu + ((u >> 16) & 1u)) >> 16;
    return (unsigned short)r;
}

// v_cvt_pk_bf16_f32: lo16=cvt(lo), hi16=cvt(hi), RNE (same rounding as f2bf)
__device__ inline unsigned int cvt_pk_bf16(float lo, float hi) {
    unsigned int r;
    asm("v_cvt_pk_bf16_f32 %0, %1, %2" : "=v"(r) : "v"(lo), "v"(hi));
    return r;
}

// async global->LDS, 16B per lane, zero VGPR round-trip
__device__ inline void gload_lds16(const void* g, void* l) {
    __builtin_amdgcn_global_load_lds(
        (const __attribute__((address_space(1))) void*)g,
        (__attribute__((address_space(3))) void*)l, 16, 0, 0);
}

// Swizzled (MFMA-fragment-order) centroid storage, hi-only:
// cluster k, dim d -> frag ((k>>5)*8 + ((k>>4)&1)*4 + (d>>5)), lane quad*16+m, elem j
__device__ inline void put_sw(unsigned short* __restrict__ swhi, int k, int d, float v) {
    int c = k >> 5, mm = k & 31;
    int mt = mm >> 4, m = mm & 15;
    int kt = d >> 5, r = d & 31;
    int quad = r >> 3, j = r & 7;
    int lane = quad * 16 + m;
    int idx = ((c * 8 + mt * 4 + kt) * 64 + lane) * 8 + j;
    swhi[idx] = f2bf(v);
}

// ---------------------------------------------------------------------------
// prep_update (per iter): [optional] cent = ihist>0 ? sums/ihist : cent;
// write fp32 cent, c_sq, swizzled bf16 hi; zero sums/ihist/cursor/inertia.
// ---------------------------------------------------------------------------
__global__ __launch_bounds__(64) void prep_update_kernel(
    const float* __restrict__ src, float* __restrict__ cent,
    float* __restrict__ sums, int* __restrict__ ihist,
    float* __restrict__ c_sq, unsigned short* __restrict__ swhi,
    int* __restrict__ cursor, float* __restrict__ inertia, int do_update) {
    int k = blockIdx.x, lane = threadIdx.x;
    float a, b;
    float cnt = (float)ihist[k];  // prev-iter counts (garbage & unused when it==0)
    if (do_update) {
        float sa = sums[k * N_F + lane], sb = sums[k * N_F + 64 + lane];
        float olda = cent[k * N_F + lane], oldb = cent[k * N_F + 64 + lane];
        a = (cnt > 0.f) ? (sa / cnt) : olda;
        b = (cnt > 0.f) ? (sb / cnt) : oldb;
    } else {
        a = src[k * N_F + lane];
        b = src[k * N_F + 64 + lane];
    }
    cent[k * N_F + lane] = a;
    cent[k * N_F + 64 + lane] = b;
    sums[k * N_F + lane] = 0.f;
    sums[k * N_F + 64 + lane] = 0.f;
    put_sw(swhi, k, lane, a);
    put_sw(swhi, k, lane + 64, b);
    float s = fmaf(a, a, b * b);
#pragma unroll
    for (int off = 32; off > 0; off >>= 1) s += __shfl_down(s, off);
    if (lane == 0) {
        c_sq[k] = s;
        ihist[k] = 0;
        cursor[k] = 0;
        if (k == 0) *inertia = 0.f;
    }
}

// ---------------------------------------------------------------------------
// assign: bf16 MFMA. A-table (128KB, fragment-ordered) double-buffered
// through LDS in 16KB eighths via global_load_lds (async DMA, zero VGPRs).
// 8 phases x 2 chunks; LDS ~37KB/block -> 4 blocks/CU (16 waves) for
// cross-block phase overlap. B = 64 samples/wave in regs.
// argmin on d2' = c_sq - 2*dot; ||x||^2 computed in-register from the
// preamble loads (quads hold disjoint 32-dim slices -> 2x shfl_xor combine).
// ---------------------------------------------------------------------------
#define CHUNK 32
#define NTN 4  // n-tiles per wave (64 samples)

__global__ __launch_bounds__(256, 4) void assign_kernel(
    const float* __restrict__ X,
    const unsigned short* __restrict__ swhi,
    const float* __restrict__ c_sq,
    float* __restrict__ labels,
    float* __restrict__ inertia,
    int* __restrict__ ihist) {
    __shared__ __align__(16) short8 a_lds[2][2 * 8 * 64];  // 2 x 16KB eighths
    __shared__ __align__(16) float csq_s[N_K];
    __shared__ int lhist[N_K];
    __shared__ float red[4];

    int t = threadIdx.x;
    int w = t >> 6, l = t & 63;
    int quad = l >> 4, l15 = l & 15;
    long long S0 = (long long)blockIdx.x * 256;

    // kick off eighth-0 DMA first (overlaps with everything below)
    {
        const char* gq = (const char*)swhi + t * 16;
        char* lq = (char*)a_lds[0] + t * 16;
#pragma unroll
        for (int i = 0; i < 4; ++i) gload_lds16(gq + i * 4096, lq + i * 4096);
    }

    for (int i = t; i < N_K; i += 256) {
        lhist[i] = 0;
        csq_s[i] = c_sq[i];
    }

    // B fragments (bf16 hi) + in-register x_sq; tail rows clamped.
    short8 bhi[NTN][4];
    float xsqv[NTN];
    long long srow[NTN];
#pragma unroll
    for (int nt = 0; nt < NTN; ++nt) {
        long long s = S0 + w * 64 + nt * 16 + l15;
        srow[nt] = s;
        long long ss = (s < N_S) ? s : (N_S - 1);
        const float4* xp = (const float4*)(X + ss * N_F);
        float sq = 0.f;
#pragma unroll
        for (int kt = 0; kt < 4; ++kt) {
            float4 va = xp[kt * 8 + quad * 2];
            float4 vb = xp[kt * 8 + quad * 2 + 1];
            float f[8] = {va.x, va.y, va.z, va.w, vb.x, vb.y, vb.z, vb.w};
            short8 h;
            unsigned int* hw = (unsigned int*)&h;
            hw[0] = cvt_pk_bf16(f[0], f[1]);
            hw[1] = cvt_pk_bf16(f[2], f[3]);
            hw[2] = cvt_pk_bf16(f[4], f[5]);
            hw[3] = cvt_pk_bf16(f[6], f[7]);
#pragma unroll
            for (int j = 0; j < 8; ++j) sq = fmaf(f[j], f[j], sq);
            bhi[nt][kt] = h;
        }
        // combine the 4 quads' partial sums (same sample across quads)
        sq += __shfl_xor(sq, 16);
        sq += __shfl_xor(sq, 32);
        xsqv[nt] = sq;
    }

    __syncthreads();  // drains vmcnt (p0 DMA + X loads), csq_s/lhist ready

    float best[NTN];
    int bestk[NTN];
#pragma unroll
    for (int nt = 0; nt < NTN; ++nt) { best[nt] = 3.4e38f; bestk[nt] = 0; }

#pragma unroll
    for (int p = 0; p < 8; ++p) {
        // issue next eighth's DMA (async; hidden under this phase's compute)
        if (p < 7) {
            const char* gq = (const char*)swhi + (p + 1) * 16384 + t * 16;
            char* lq = (char*)a_lds[(p + 1) & 1] + t * 16;
#pragma unroll
            for (int i = 0; i < 4; ++i) gload_lds16(gq + i * 4096, lq + i * 4096);
        }

        const short8* abase = a_lds[p & 1] + l;
#pragma unroll
        for (int cc = 0; cc < 2; ++cc) {
            int c = p * 2 + cc;
            floatx4 acc[2][NTN];
#pragma unroll
            for (int mt = 0; mt < 2; ++mt)
#pragma unroll
                for (int nt = 0; nt < NTN; ++nt) acc[mt][nt] = (floatx4){0.f, 0.f, 0.f, 0.f};

#pragma unroll
            for (int kt = 0; kt < 4; ++kt) {
                short8 a0 = abase[(cc * 8 + kt) * 64];
                short8 a1 = abase[(cc * 8 + 4 + kt) * 64];
#pragma unroll
                for (int nt = 0; nt < NTN; ++nt) {
                    acc[0][nt] = __builtin_amdgcn_mfma_f32_16x16x32_bf16(a0, bhi[nt][kt], acc[0][nt], 0, 0, 0);
                    acc[1][nt] = __builtin_amdgcn_mfma_f32_16x16x32_bf16(a1, bhi[nt][kt], acc[1][nt], 0, 0, 0);
                }
            }

#pragma unroll
            for (int mt = 0; mt < 2; ++mt) {
                float4 cs = ((const float4*)csq_s)[c * 8 + mt * 4 + quad];
#pragma unroll
                for (int r = 0; r < 4; ++r) {
                    float csr = (r == 0) ? cs.x : (r == 1) ? cs.y : (r == 2) ? cs.z : cs.w;
                    int kg = c * CHUNK + mt * 16 + quad * 4 + r;
#pragma unroll
                    for (int nt = 0; nt < NTN; ++nt) {
                        float d2 = fmaf(-2.f, acc[mt][nt][r], csr);
                        if (d2 < best[nt]) { best[nt] = d2; bestk[nt] = kg; }
                    }
                }
            }
        }

        if (p < 7) __syncthreads();  // stage of p+1 landed; all done reading buf[p&1]
    }

    // combine 4 quads per sample column (tie -> smaller k)
#pragma unroll
    for (int nt = 0; nt < NTN; ++nt) {
#pragma unroll
        for (int off = 16; off < 64; off <<= 1) {
            float ob = __shfl_xor(best[nt], off);
            int ok = __shfl_xor(bestk[nt], off);
            if (ob < best[nt] || (ob == best[nt] && ok < bestk[nt])) {
                best[nt] = ob;
                bestk[nt] = ok;
            }
        }
    }

    float contrib = 0.f;
    if (quad == 0) {
#pragma unroll
        for (int nt = 0; nt < NTN; ++nt) {
            if (srow[nt] < N_S) {
                labels[srow[nt]] = (float)bestk[nt];
                atomicAdd(&lhist[bestk[nt]], 1);
                contrib += fmaxf(xsqv[nt] + best[nt], 0.f);
            }
        }
    }
#pragma unroll
    for (int off = 32; off > 0; off >>= 1) contrib += __shfl_down(contrib, off);
    if (l == 0) red[w] = contrib;
    __syncthreads();
    if (t == 0) atomicAdd(inertia, red[0] + red[1] + red[2] + red[3]);

    for (int i = t; i < N_K; i += 256) {
        int v = lhist[i];
        if (v) atomicAdd(&ihist[i], v);
    }
}

// ---------------------------------------------------------------------------
// scatter (per iter): block-aggregated counting-sort scatter, 4 samples/thread.
// Each block redundantly computes the exclusive prefix of ihist in LDS.
// order entries are PACKED: (row << 9) | cluster  (row < 400000 -> fits int).
// ---------------------------------------------------------------------------
__global__ __launch_bounds__(256) void scatter_kernel(const float* __restrict__ labels,
                                                      const int* __restrict__ ihist,
                                                      int* __restrict__ cursor,
                                                      int* __restrict__ order) {
    __shared__ int lhist[N_K];
    __shared__ int excl[N_K];
    __shared__ int lbase[N_K];
    __shared__ int wtot[4];
    int t = threadIdx.x;
    long long i0 = (long long)blockIdx.x * 1024 + (long long)t * 4;

    for (int j = t; j < N_K; j += 256) lhist[j] = 0;

    // exclusive prefix of ihist[512] with 256 threads (2 entries each)
    int v0 = ihist[2 * t], v1 = ihist[2 * t + 1];
    int s = v0 + v1;
    int x = s;
    int lane = t & 63, w = t >> 6;
#pragma unroll
    for (int off = 1; off < 64; off <<= 1) {
        int y = __shfl_up(x, off);
        if (lane >= off) x += y;
    }
    if (lane == 63) wtot[w] = x;
    __syncthreads();  // lhist zeroed + wtot ready
    int woff = 0;
    for (int ww = 0; ww < w; ++ww) woff += wtot[ww];
    int ex = woff + x - s;
    excl[2 * t] = ex;
    excl[2 * t + 1] = ex + v0;

    int k0 = 0, k1 = 0, k2 = 0, k3 = 0, r0 = 0, r1 = 0, r2 = 0, r3 = 0;
    bool valid = (i0 < N_S);  // N_S % 4 == 0 -> whole quad valid or not
    if (valid) {
        float4 lab = *(const float4*)(labels + i0);
        k0 = (int)lab.x; k1 = (int)lab.y; k2 = (int)lab.z; k3 = (int)lab.w;
        r0 = atomicAdd(&lhist[k0], 1);
        r1 = atomicAdd(&lhist[k1], 1);
        r2 = atomicAdd(&lhist[k2], 1);
        r3 = atomicAdd(&lhist[k3], 1);
    }
    __syncthreads();  // lhist final + excl written
    for (int j = t; j < N_K; j += 256) {
        int c = lhist[j];
        lbase[j] = c ? (excl[j] + atomicAdd(&cursor[j], c)) : 0;
    }
    __syncthreads();
    if (valid) {
        int i = (int)i0;
        order[lbase[k0] + r0] = ((i + 0) << 9) | k0;
        order[lbase[k1] + r1] = ((i + 1) << 9) | k1;
        order[lbase[k2] + r2] = ((i + 2) << 9) | k2;
        order[lbase[k3] + r3] = ((i + 3) << 9) | k3;
    }
}

// ---------------------------------------------------------------------------
// csum (per iter): float4 gather-accumulate over packed order[] windows.
// RPB=128 (400000/128=3125 blocks exactly, no tail); 8 groups x 16 rows,
// 32 dim-threads per group; cluster id unpacked from order (no label gather).
// ---------------------------------------------------------------------------
#define RPB 128
#define RPG 16

__device__ inline void flush4(float* __restrict__ sums, int k, int dbase, float4 acc) {
    float* sp = sums + k * N_F + dbase;
    atomicAdd(sp + 0, acc.x);
    atomicAdd(sp + 1, acc.y);
    atomicAdd(sp + 2, acc.z);
    atomicAdd(sp + 3, acc.w);
}

__global__ __launch_bounds__(256) void csum_kernel(const float* __restrict__ X,
                                                   const int* __restrict__ order,
                                                   float* __restrict__ sums) {
    __shared__ int ord_s[RPB];
    int t = threadIdx.x;
    int r0 = blockIdx.x * RPB;
    if (t < RPB) ord_s[t] = order[r0 + t];
    __syncthreads();

    int g = t >> 5;              // 8 groups of 16 rows
    int dbase = (t & 31) << 2;   // 4 dims per thread
    const float* Xd = X + dbase;
    int base = g * RPG;

    float4 acc = {0.f, 0.f, 0.f, 0.f};
    int kcur = ord_s[base] & 511;
    if (kcur == (ord_s[base + RPG - 1] & 511)) {
        // fast path: whole group range is one cluster (order is k-monotone)
#pragma unroll
        for (int i = 0; i < RPG; ++i) {
            int row = ord_s[base + i] >> 9;
            const float4 v = *(const float4*)(Xd + (long long)row * N_F);
            acc.x += v.x; acc.y += v.y; acc.z += v.z; acc.w += v.w;
        }
        flush4(sums, kcur, dbase, acc);
    } else {
        for (int i = 0; i < RPG; ++i) {
            int e = ord_s[base + i];
            int k = e & 511;
            if (k != kcur) {
                flush4(sums, kcur, dbase, acc);
                acc = (float4){0.f, 0.f, 0.f, 0.f};
                kcur = k;
            }
            const float4 v = *(const float4*)(Xd + (long long)(e >> 9) * N_F);
            acc.x += v.x; acc.y += v.y; acc.z += v.z; acc.w += v.w;
        }
        flush4(sums, kcur, dbase, acc);
    }
}

// ---------------------------------------------------------------------------
// final update: cent = ihist>0 ? sums/ihist : cent
// ---------------------------------------------------------------------------
__global__ __launch_bounds__(128) void update_kernel(const float* __restrict__ sums,
                                                     const int* __restrict__ ihist,
                                                     float* __restrict__ cent) {
    int k = blockIdx.x;
    int d = threadIdx.x;
    float c = (float)ihist[k];
    float s = sums[k * N_F + d];
    float old = cent[k * N_F + d];
    cent[k * N_F + d] = (c > 0.f) ? (s / c) : old;
}

extern "C" void kernel_launch(void* const* d_in, const int* in_sizes, int n_in,
                              void* d_out, int out_size, void* d_ws, size_t ws_size,
                              hipStream_t stream) {
    const float* X = (const float*)d_in[0];
    const float* initc = (const float*)d_in[1];

    float* out = (float*)d_out;
    float* cent = out;                // [512*128] (output 0)
    float* labels = out + N_K * N_F;  // [400000]  (output 1)
    float* inertia = labels + N_S;    // [1]       (output 2)

    float* c_sq = (float*)d_ws;                           // 512 f
    float* sums = c_sq + N_K;                             // (512+1)*128 f
    unsigned short* swhi = (unsigned short*)(sums + (N_K + 1) * N_F);  // 65536 ush
    int* ihist = (int*)(swhi + N_K * N_F);                // 512 i
    int* cursor = ihist + N_K;                            // 512 i
    int* order = cursor + N_K;                            // 400000 i (packed row<<9|k)

    for (int it = 0; it < ITERS; ++it) {
        prep_update_kernel<<<N_K, 64, 0, stream>>>(initc, cent, sums, ihist, c_sq,
                                                   swhi, cursor, inertia, it > 0);
        assign_kernel<<<(N_S + 255) / 256, 256, 0, stream>>>(X, swhi, c_sq,
                                                             labels, inertia, ihist);
        scatter_kernel<<<(N_S + 1023) / 1024, 256, 0, stream>>>(labels, ihist, cursor, order);
        csum_kernel<<<N_S / RPB, 256, 0, stream>>>(X, order, sums);
    }
    update_kernel<<<N_K, N_F, 0, stream>>>(sums, ihist, cent);
}

// Round 8
// 2456.657 us; speedup vs baseline: 1.0885x; 1.0885x over previous
//
#include <hip/hip_runtime.h>

#define N_S 400000
#define N_F 128
#define N_K 512
#define ITERS 10

typedef __attribute__((ext_vector_type(8))) short short8;
typedef __attribute__((ext_vector_type(4))) float floatx4;

__device__ inline unsigned short f2bf(float f) {
    unsigned int u = __float_as_uint(f);
    unsigned int r = (u + 0x7FFFu + ((u >> 16) & 1u)) >> 16;
    return (unsigned short)r;
}

// v_cvt_pk_bf16_f32: lo16=cvt(lo), hi16=cvt(hi), RNE (same rounding as f2bf)
__device__ inline unsigned int cvt_pk_bf16(float lo, float hi) {
    unsigned int r;
    asm("v_cvt_pk_bf16_f32 %0, %1, %2" : "=v"(r) : "v"(lo), "v"(hi));
    return r;
}

// async global->LDS, 16B per lane, zero VGPR round-trip
__device__ inline void gload_lds16(const void* g, void* l) {
    __builtin_amdgcn_global_load_lds(
        (const __attribute__((address_space(1))) void*)g,
        (__attribute__((address_space(3))) void*)l, 16, 0, 0);
}

// Swizzled (MFMA-fragment-order) centroid storage, hi-only:
// cluster k, dim d -> frag ((k>>5)*8 + ((k>>4)&1)*4 + (d>>5)), lane quad*16+m, elem j
__device__ inline void put_sw(unsigned short* __restrict__ swhi, int k, int d, float v) {
    int c = k >> 5, mm = k & 31;
    int mt = mm >> 4, m = mm & 15;
    int kt = d >> 5, r = d & 31;
    int quad = r >> 3, j = r & 7;
    int lane = quad * 16 + m;
    int idx = ((c * 8 + mt * 4 + kt) * 64 + lane) * 8 + j;
    swhi[idx] = f2bf(v);
}

// ---------------------------------------------------------------------------
// prep_update (per iter): [optional] cent = ihist>0 ? sums/ihist : cent;
// write fp32 cent, c_sq, swizzled bf16 hi; zero sums/ihist/cursor/inertia.
// ---------------------------------------------------------------------------
__global__ __launch_bounds__(64) void prep_update_kernel(
    const float* __restrict__ src, float* __restrict__ cent,
    float* __restrict__ sums, int* __restrict__ ihist,
    float* __restrict__ c_sq, unsigned short* __restrict__ swhi,
    int* __restrict__ cursor, float* __restrict__ inertia, int do_update) {
    int k = blockIdx.x, lane = threadIdx.x;
    float a, b;
    float cnt = (float)ihist[k];  // prev-iter counts (garbage & unused when it==0)
    if (do_update) {
        float sa = sums[k * N_F + lane], sb = sums[k * N_F + 64 + lane];
        float olda = cent[k * N_F + lane], oldb = cent[k * N_F + 64 + lane];
        a = (cnt > 0.f) ? (sa / cnt) : olda;
        b = (cnt > 0.f) ? (sb / cnt) : oldb;
    } else {
        a = src[k * N_F + lane];
        b = src[k * N_F + 64 + lane];
    }
    cent[k * N_F + lane] = a;
    cent[k * N_F + 64 + lane] = b;
    sums[k * N_F + lane] = 0.f;
    sums[k * N_F + 64 + lane] = 0.f;
    put_sw(swhi, k, lane, a);
    put_sw(swhi, k, lane + 64, b);
    float s = fmaf(a, a, b * b);
#pragma unroll
    for (int off = 32; off > 0; off >>= 1) s += __shfl_down(s, off);
    if (lane == 0) {
        c_sq[k] = s;
        ihist[k] = 0;
        cursor[k] = 0;
        if (k == 0) *inertia = 0.f;
    }
}

// ---------------------------------------------------------------------------
// assign: bf16 MFMA. A-table (128KB, fragment-ordered) double-buffered
// through LDS in 16KB eighths via global_load_lds (async DMA, zero VGPRs).
// 8 phases x 2 chunks; LDS ~37KB/block -> 4 blocks/CU (16 waves) for
// cross-block phase overlap. B = 64 samples/wave in regs.
// argmin on d2' = c_sq - 2*dot; ||x||^2 computed in-register from the
// preamble loads (quads hold disjoint 32-dim slices -> 2x shfl_xor combine).
// (Ran successfully in round-5 bench; unchanged.)
// ---------------------------------------------------------------------------
#define CHUNK 32
#define NTN 4  // n-tiles per wave (64 samples)

__global__ __launch_bounds__(256, 4) void assign_kernel(
    const float* __restrict__ X,
    const unsigned short* __restrict__ swhi,
    const float* __restrict__ c_sq,
    float* __restrict__ labels,
    float* __restrict__ inertia,
    int* __restrict__ ihist) {
    __shared__ __align__(16) short8 a_lds[2][2 * 8 * 64];  // 2 x 16KB eighths
    __shared__ __align__(16) float csq_s[N_K];
    __shared__ int lhist[N_K];
    __shared__ float red[4];

    int t = threadIdx.x;
    int w = t >> 6, l = t & 63;
    int quad = l >> 4, l15 = l & 15;
    long long S0 = (long long)blockIdx.x * 256;

    // kick off eighth-0 DMA first (overlaps with everything below)
    {
        const char* gq = (const char*)swhi + t * 16;
        char* lq = (char*)a_lds[0] + t * 16;
#pragma unroll
        for (int i = 0; i < 4; ++i) gload_lds16(gq + i * 4096, lq + i * 4096);
    }

    for (int i = t; i < N_K; i += 256) {
        lhist[i] = 0;
        csq_s[i] = c_sq[i];
    }

    // B fragments (bf16 hi) + in-register x_sq; tail rows clamped.
    short8 bhi[NTN][4];
    float xsqv[NTN];
    long long srow[NTN];
#pragma unroll
    for (int nt = 0; nt < NTN; ++nt) {
        long long s = S0 + w * 64 + nt * 16 + l15;
        srow[nt] = s;
        long long ss = (s < N_S) ? s : (N_S - 1);
        const float4* xp = (const float4*)(X + ss * N_F);
        float sq = 0.f;
#pragma unroll
        for (int kt = 0; kt < 4; ++kt) {
            float4 va = xp[kt * 8 + quad * 2];
            float4 vb = xp[kt * 8 + quad * 2 + 1];
            float f[8] = {va.x, va.y, va.z, va.w, vb.x, vb.y, vb.z, vb.w};
            short8 h;
            unsigned int* hw = (unsigned int*)&h;
            hw[0] = cvt_pk_bf16(f[0], f[1]);
            hw[1] = cvt_pk_bf16(f[2], f[3]);
            hw[2] = cvt_pk_bf16(f[4], f[5]);
            hw[3] = cvt_pk_bf16(f[6], f[7]);
#pragma unroll
            for (int j = 0; j < 8; ++j) sq = fmaf(f[j], f[j], sq);
            bhi[nt][kt] = h;
        }
        // combine the 4 quads' partial sums (same sample across quads)
        sq += __shfl_xor(sq, 16);
        sq += __shfl_xor(sq, 32);
        xsqv[nt] = sq;
    }

    __syncthreads();  // drains vmcnt (p0 DMA + X loads), csq_s/lhist ready

    float best[NTN];
    int bestk[NTN];
#pragma unroll
    for (int nt = 0; nt < NTN; ++nt) { best[nt] = 3.4e38f; bestk[nt] = 0; }

#pragma unroll
    for (int p = 0; p < 8; ++p) {
        // issue next eighth's DMA (async; hidden under this phase's compute)
        if (p < 7) {
            const char* gq = (const char*)swhi + (p + 1) * 16384 + t * 16;
            char* lq = (char*)a_lds[(p + 1) & 1] + t * 16;
#pragma unroll
            for (int i = 0; i < 4; ++i) gload_lds16(gq + i * 4096, lq + i * 4096);
        }

        const short8* abase = a_lds[p & 1] + l;
#pragma unroll
        for (int cc = 0; cc < 2; ++cc) {
            int c = p * 2 + cc;
            floatx4 acc[2][NTN];
#pragma unroll
            for (int mt = 0; mt < 2; ++mt)
#pragma unroll
                for (int nt = 0; nt < NTN; ++nt) acc[mt][nt] = (floatx4){0.f, 0.f, 0.f, 0.f};

#pragma unroll
            for (int kt = 0; kt < 4; ++kt) {
                short8 a0 = abase[(cc * 8 + kt) * 64];
                short8 a1 = abase[(cc * 8 + 4 + kt) * 64];
#pragma unroll
                for (int nt = 0; nt < NTN; ++nt) {
                    acc[0][nt] = __builtin_amdgcn_mfma_f32_16x16x32_bf16(a0, bhi[nt][kt], acc[0][nt], 0, 0, 0);
                    acc[1][nt] = __builtin_amdgcn_mfma_f32_16x16x32_bf16(a1, bhi[nt][kt], acc[1][nt], 0, 0, 0);
                }
            }

#pragma unroll
            for (int mt = 0; mt < 2; ++mt) {
                float4 cs = ((const float4*)csq_s)[c * 8 + mt * 4 + quad];
#pragma unroll
                for (int r = 0; r < 4; ++r) {
                    float csr = (r == 0) ? cs.x : (r == 1) ? cs.y : (r == 2) ? cs.z : cs.w;
                    int kg = c * CHUNK + mt * 16 + quad * 4 + r;
#pragma unroll
                    for (int nt = 0; nt < NTN; ++nt) {
                        float d2 = fmaf(-2.f, acc[mt][nt][r], csr);
                        if (d2 < best[nt]) { best[nt] = d2; bestk[nt] = kg; }
                    }
                }
            }
        }

        if (p < 7) __syncthreads();  // stage of p+1 landed; all done reading buf[p&1]
    }

    // combine 4 quads per sample column (tie -> smaller k)
#pragma unroll
    for (int nt = 0; nt < NTN; ++nt) {
#pragma unroll
        for (int off = 16; off < 64; off <<= 1) {
            float ob = __shfl_xor(best[nt], off);
            int ok = __shfl_xor(bestk[nt], off);
            if (ob < best[nt] || (ob == best[nt] && ok < bestk[nt])) {
                best[nt] = ob;
                bestk[nt] = ok;
            }
        }
    }

    float contrib = 0.f;
    if (quad == 0) {
#pragma unroll
        for (int nt = 0; nt < NTN; ++nt) {
            if (srow[nt] < N_S) {
                labels[srow[nt]] = (float)bestk[nt];
                atomicAdd(&lhist[bestk[nt]], 1);
                contrib += fmaxf(xsqv[nt] + best[nt], 0.f);
            }
        }
    }
#pragma unroll
    for (int off = 32; off > 0; off >>= 1) contrib += __shfl_down(contrib, off);
    if (l == 0) red[w] = contrib;
    __syncthreads();
    if (t == 0) atomicAdd(inertia, red[0] + red[1] + red[2] + red[3]);

    for (int i = t; i < N_K; i += 256) {
        int v = lhist[i];
        if (v) atomicAdd(&ihist[i], v);
    }
}

// ---------------------------------------------------------------------------
// scatter (per iter): block-aggregated counting-sort scatter, 4 samples/thread.
// Each block redundantly computes the exclusive prefix of ihist in LDS;
// block 0 additionally publishes it as offsets[] for csum.
// order entries are PACKED: (row << 9) | cluster  (row < 400000 -> fits int).
// ---------------------------------------------------------------------------
__global__ __launch_bounds__(256) void scatter_kernel(const float* __restrict__ labels,
                                                      const int* __restrict__ ihist,
                                                      int* __restrict__ cursor,
                                                      int* __restrict__ order,
                                                      int* __restrict__ offsets) {
    __shared__ int lhist[N_K];
    __shared__ int excl[N_K];
    __shared__ int lbase[N_K];
    __shared__ int wtot[4];
    int t = threadIdx.x;
    long long i0 = (long long)blockIdx.x * 1024 + (long long)t * 4;

    for (int j = t; j < N_K; j += 256) lhist[j] = 0;

    // exclusive prefix of ihist[512] with 256 threads (2 entries each)
    int v0 = ihist[2 * t], v1 = ihist[2 * t + 1];
    int s = v0 + v1;
    int x = s;
    int lane = t & 63, w = t >> 6;
#pragma unroll
    for (int off = 1; off < 64; off <<= 1) {
        int y = __shfl_up(x, off);
        if (lane >= off) x += y;
    }
    if (lane == 63) wtot[w] = x;
    __syncthreads();  // lhist zeroed + wtot ready
    int woff = 0;
    for (int ww = 0; ww < w; ++ww) woff += wtot[ww];
    int ex = woff + x - s;
    excl[2 * t] = ex;
    excl[2 * t + 1] = ex + v0;
    if (blockIdx.x == 0) {
        offsets[2 * t] = ex;
        offsets[2 * t + 1] = ex + v0;
    }

    int k0 = 0, k1 = 0, k2 = 0, k3 = 0, r0 = 0, r1 = 0, r2 = 0, r3 = 0;
    bool valid = (i0 < N_S);  // N_S % 4 == 0 -> whole quad valid or not
    if (valid) {
        float4 lab = *(const float4*)(labels + i0);
        k0 = (int)lab.x; k1 = (int)lab.y; k2 = (int)lab.z; k3 = (int)lab.w;
        r0 = atomicAdd(&lhist[k0], 1);
        r1 = atomicAdd(&lhist[k1], 1);
        r2 = atomicAdd(&lhist[k2], 1);
        r3 = atomicAdd(&lhist[k3], 1);
    }
    __syncthreads();  // lhist final + excl written
    for (int j = t; j < N_K; j += 256) {
        int c = lhist[j];
        lbase[j] = c ? (excl[j] + atomicAdd(&cursor[j], c)) : 0;
    }
    __syncthreads();
    if (valid) {
        int i = (int)i0;
        order[lbase[k0] + r0] = ((i + 0) << 9) | k0;
        order[lbase[k1] + r1] = ((i + 1) << 9) | k1;
        order[lbase[k2] + r2] = ((i + 2) << 9) | k2;
        order[lbase[k3] + r3] = ((i + 3) << 9) | k3;
    }
}

// ---------------------------------------------------------------------------
// csum (per iter): per-cluster-chunk blocks, atomic-lean.
// grid = N_K * 4; block (k, chunk) sums its quarter of cluster k's rows
// (order is cluster-sorted; offsets from scatter). 8 row-groups x 32
// dim-threads x float4; group partials reduced via 4KB LDS; ONE atomicAdd
// per dim per block (128/block, ~262K total vs 1.66M in the window scheme).
// All early returns are block-uniform (offsets/blockIdx only).
// ---------------------------------------------------------------------------
#define CSUM_C 4  // chunks per cluster

__global__ __launch_bounds__(256) void csum_kernel(const float* __restrict__ X,
                                                   const int* __restrict__ order,
                                                   const int* __restrict__ offsets,
                                                   float* __restrict__ sums) {
    __shared__ float part[8][N_F];
    int t = threadIdx.x;
    int k = blockIdx.x >> 2, chunk = blockIdx.x & 3;
    int s0 = offsets[k];
    int e0 = (k < N_K - 1) ? offsets[k + 1] : N_S;
    int cnt = e0 - s0;
    if (cnt <= 0) return;  // block-uniform
    int len = (cnt + CSUM_C - 1) >> 2;
    int s = s0 + chunk * len;
    int e = min(s + len, e0);
    if (s >= e) return;  // block-uniform (only when cnt < chunk index reach)

    int g = t >> 5;              // 8 groups; group g does rows s+g, s+g+8, ...
    int dbase = (t & 31) << 2;   // 4 dims per thread (float4)
    const float* Xd = X + dbase;

    float4 acc = {0.f, 0.f, 0.f, 0.f};
    for (int r = s + g; r < e; r += 8) {
        int row = order[r] >> 9;  // same addr for the group's 32 lanes -> broadcast
        const float4 v = *(const float4*)(Xd + (long long)row * N_F);
        acc.x += v.x; acc.y += v.y; acc.z += v.z; acc.w += v.w;
    }
    *(float4*)&part[g][dbase] = acc;
    __syncthreads();

    if (t < N_F) {
        float r = 0.f;
#pragma unroll
        for (int gg = 0; gg < 8; ++gg) r += part[gg][t];
        atomicAdd(&sums[k * N_F + t], r);
    }
}

// ---------------------------------------------------------------------------
// final update: cent = ihist>0 ? sums/ihist : cent
// ---------------------------------------------------------------------------
__global__ __launch_bounds__(128) void update_kernel(const float* __restrict__ sums,
                                                     const int* __restrict__ ihist,
                                                     float* __restrict__ cent) {
    int k = blockIdx.x;
    int d = threadIdx.x;
    float c = (float)ihist[k];
    float s = sums[k * N_F + d];
    float old = cent[k * N_F + d];
    cent[k * N_F + d] = (c > 0.f) ? (s / c) : old;
}

extern "C" void kernel_launch(void* const* d_in, const int* in_sizes, int n_in,
                              void* d_out, int out_size, void* d_ws, size_t ws_size,
                              hipStream_t stream) {
    const float* X = (const float*)d_in[0];
    const float* initc = (const float*)d_in[1];

    float* out = (float*)d_out;
    float* cent = out;                // [512*128] (output 0)
    float* labels = out + N_K * N_F;  // [400000]  (output 1)
    float* inertia = labels + N_S;    // [1]       (output 2)

    float* c_sq = (float*)d_ws;                           // 512 f
    float* sums = c_sq + N_K;                             // (512+1)*128 f
    unsigned short* swhi = (unsigned short*)(sums + (N_K + 1) * N_F);  // 65536 ush
    int* ihist = (int*)(swhi + N_K * N_F);                // 512 i
    int* cursor = ihist + N_K;                            // 512 i
    int* offsets = cursor + N_K;                          // 512 i
    int* order = offsets + N_K;                           // 400000 i (packed row<<9|k)

    for (int it = 0; it < ITERS; ++it) {
        prep_update_kernel<<<N_K, 64, 0, stream>>>(initc, cent, sums, ihist, c_sq,
                                                   swhi, cursor, inertia, it > 0);
        assign_kernel<<<(N_S + 255) / 256, 256, 0, stream>>>(X, swhi, c_sq,
                                                             labels, inertia, ihist);
        scatter_kernel<<<(N_S + 1023) / 1024, 256, 0, stream>>>(labels, ihist, cursor,
                                                                order, offsets);
        csum_kernel<<<N_K * CSUM_C, 256, 0, stream>>>(X, order, offsets, sums);
    }
    update_kernel<<<N_K, N_F, 0, stream>>>(sums, ihist, cent);
}

// Round 9
// 2198.929 us; speedup vs baseline: 1.2161x; 1.1172x over previous
//
#include <hip/hip_runtime.h>

#define N_S 400000
#define N_F 128
#define N_K 512
#define ITERS 10

typedef __attribute__((ext_vector_type(8))) short short8;
typedef __attribute__((ext_vector_type(4))) float floatx4;

__device__ inline unsigned short f2bf(float f) {
    unsigned int u = __float_as_uint(f);
    unsigned int r = (u + 0x7FFFu + ((u >> 16) & 1u)) >> 16;
    return (unsigned short)r;
}

// v_cvt_pk_bf16_f32: lo16=cvt(lo), hi16=cvt(hi), RNE (same rounding as f2bf)
__device__ inline unsigned int cvt_pk_bf16(float lo, float hi) {
    unsigned int r;
    asm("v_cvt_pk_bf16_f32 %0, %1, %2" : "=v"(r) : "v"(lo), "v"(hi));
    return r;
}

// async global->LDS, 16B per lane, zero VGPR round-trip
__device__ inline void gload_lds16(const void* g, void* l) {
    __builtin_amdgcn_global_load_lds(
        (const __attribute__((address_space(1))) void*)g,
        (__attribute__((address_space(3))) void*)l, 16, 0, 0);
}

// Swizzled (MFMA-fragment-order) centroid storage, hi-only:
// cluster k, dim d -> frag ((k>>5)*8 + ((k>>4)&1)*4 + (d>>5)), lane quad*16+m, elem j
__device__ inline void put_sw(unsigned short* __restrict__ swhi, int k, int d, float v) {
    int c = k >> 5, mm = k & 31;
    int mt = mm >> 4, m = mm & 15;
    int kt = d >> 5, r = d & 31;
    int quad = r >> 3, j = r & 7;
    int lane = quad * 16 + m;
    int idx = ((c * 8 + mt * 4 + kt) * 64 + lane) * 8 + j;
    swhi[idx] = f2bf(v);
}

// ---------------------------------------------------------------------------
// prep_update (per iter): [optional] cent = ihist>0 ? sums/ihist : cent;
// write fp32 cent, c_sq, swizzled bf16 hi; zero sums/ihist/cursor/inertia.
// ---------------------------------------------------------------------------
__global__ __launch_bounds__(64) void prep_update_kernel(
    const float* __restrict__ src, float* __restrict__ cent,
    float* __restrict__ sums, int* __restrict__ ihist,
    float* __restrict__ c_sq, unsigned short* __restrict__ swhi,
    int* __restrict__ cursor, float* __restrict__ inertia, int do_update) {
    int k = blockIdx.x, lane = threadIdx.x;
    float a, b;
    float cnt = (float)ihist[k];  // prev-iter counts (garbage & unused when it==0)
    if (do_update) {
        float sa = sums[k * N_F + lane], sb = sums[k * N_F + 64 + lane];
        float olda = cent[k * N_F + lane], oldb = cent[k * N_F + 64 + lane];
        a = (cnt > 0.f) ? (sa / cnt) : olda;
        b = (cnt > 0.f) ? (sb / cnt) : oldb;
    } else {
        a = src[k * N_F + lane];
        b = src[k * N_F + 64 + lane];
    }
    cent[k * N_F + lane] = a;
    cent[k * N_F + 64 + lane] = b;
    sums[k * N_F + lane] = 0.f;
    sums[k * N_F + 64 + lane] = 0.f;
    put_sw(swhi, k, lane, a);
    put_sw(swhi, k, lane + 64, b);
    float s = fmaf(a, a, b * b);
#pragma unroll
    for (int off = 32; off > 0; off >>= 1) s += __shfl_down(s, off);
    if (lane == 0) {
        c_sq[k] = s;
        ihist[k] = 0;
        cursor[k] = 0;
        if (k == 0) *inertia = 0.f;
    }
}

// ---------------------------------------------------------------------------
// assign: bf16 MFMA. A-table (128KB, fragment-ordered) double-buffered
// through LDS in 16KB eighths via global_load_lds (async DMA, zero VGPRs).
// 8 phases x 2 chunks; LDS ~37KB/block -> 4 blocks/CU (16 waves).
// B = 64 samples/wave in regs. argmin on d2' = c_sq - 2*dot.
// (Ran successfully in rounds 5/8; unchanged.)
// ---------------------------------------------------------------------------
#define CHUNK 32
#define NTN 4  // n-tiles per wave (64 samples)

__global__ __launch_bounds__(256, 4) void assign_kernel(
    const float* __restrict__ X,
    const unsigned short* __restrict__ swhi,
    const float* __restrict__ c_sq,
    float* __restrict__ labels,
    float* __restrict__ inertia,
    int* __restrict__ ihist) {
    __shared__ __align__(16) short8 a_lds[2][2 * 8 * 64];  // 2 x 16KB eighths
    __shared__ __align__(16) float csq_s[N_K];
    __shared__ int lhist[N_K];
    __shared__ float red[4];

    int t = threadIdx.x;
    int w = t >> 6, l = t & 63;
    int quad = l >> 4, l15 = l & 15;
    long long S0 = (long long)blockIdx.x * 256;

    // kick off eighth-0 DMA first (overlaps with everything below)
    {
        const char* gq = (const char*)swhi + t * 16;
        char* lq = (char*)a_lds[0] + t * 16;
#pragma unroll
        for (int i = 0; i < 4; ++i) gload_lds16(gq + i * 4096, lq + i * 4096);
    }

    for (int i = t; i < N_K; i += 256) {
        lhist[i] = 0;
        csq_s[i] = c_sq[i];
    }

    // B fragments (bf16 hi) + in-register x_sq; tail rows clamped.
    short8 bhi[NTN][4];
    float xsqv[NTN];
    long long srow[NTN];
#pragma unroll
    for (int nt = 0; nt < NTN; ++nt) {
        long long s = S0 + w * 64 + nt * 16 + l15;
        srow[nt] = s;
        long long ss = (s < N_S) ? s : (N_S - 1);
        const float4* xp = (const float4*)(X + ss * N_F);
        float sq = 0.f;
#pragma unroll
        for (int kt = 0; kt < 4; ++kt) {
            float4 va = xp[kt * 8 + quad * 2];
            float4 vb = xp[kt * 8 + quad * 2 + 1];
            float f[8] = {va.x, va.y, va.z, va.w, vb.x, vb.y, vb.z, vb.w};
            short8 h;
            unsigned int* hw = (unsigned int*)&h;
            hw[0] = cvt_pk_bf16(f[0], f[1]);
            hw[1] = cvt_pk_bf16(f[2], f[3]);
            hw[2] = cvt_pk_bf16(f[4], f[5]);
            hw[3] = cvt_pk_bf16(f[6], f[7]);
#pragma unroll
            for (int j = 0; j < 8; ++j) sq = fmaf(f[j], f[j], sq);
            bhi[nt][kt] = h;
        }
        // combine the 4 quads' partial sums (same sample across quads)
        sq += __shfl_xor(sq, 16);
        sq += __shfl_xor(sq, 32);
        xsqv[nt] = sq;
    }

    __syncthreads();  // drains vmcnt (p0 DMA + X loads), csq_s/lhist ready

    float best[NTN];
    int bestk[NTN];
#pragma unroll
    for (int nt = 0; nt < NTN; ++nt) { best[nt] = 3.4e38f; bestk[nt] = 0; }

#pragma unroll
    for (int p = 0; p < 8; ++p) {
        // issue next eighth's DMA (async; hidden under this phase's compute)
        if (p < 7) {
            const char* gq = (const char*)swhi + (p + 1) * 16384 + t * 16;
            char* lq = (char*)a_lds[(p + 1) & 1] + t * 16;
#pragma unroll
            for (int i = 0; i < 4; ++i) gload_lds16(gq + i * 4096, lq + i * 4096);
        }

        const short8* abase = a_lds[p & 1] + l;
#pragma unroll
        for (int cc = 0; cc < 2; ++cc) {
            int c = p * 2 + cc;
            floatx4 acc[2][NTN];
#pragma unroll
            for (int mt = 0; mt < 2; ++mt)
#pragma unroll
                for (int nt = 0; nt < NTN; ++nt) acc[mt][nt] = (floatx4){0.f, 0.f, 0.f, 0.f};

#pragma unroll
            for (int kt = 0; kt < 4; ++kt) {
                short8 a0 = abase[(cc * 8 + kt) * 64];
                short8 a1 = abase[(cc * 8 + 4 + kt) * 64];
#pragma unroll
                for (int nt = 0; nt < NTN; ++nt) {
                    acc[0][nt] = __builtin_amdgcn_mfma_f32_16x16x32_bf16(a0, bhi[nt][kt], acc[0][nt], 0, 0, 0);
                    acc[1][nt] = __builtin_amdgcn_mfma_f32_16x16x32_bf16(a1, bhi[nt][kt], acc[1][nt], 0, 0, 0);
                }
            }

#pragma unroll
            for (int mt = 0; mt < 2; ++mt) {
                float4 cs = ((const float4*)csq_s)[c * 8 + mt * 4 + quad];
#pragma unroll
                for (int r = 0; r < 4; ++r) {
                    float csr = (r == 0) ? cs.x : (r == 1) ? cs.y : (r == 2) ? cs.z : cs.w;
                    int kg = c * CHUNK + mt * 16 + quad * 4 + r;
#pragma unroll
                    for (int nt = 0; nt < NTN; ++nt) {
                        float d2 = fmaf(-2.f, acc[mt][nt][r], csr);
                        if (d2 < best[nt]) { best[nt] = d2; bestk[nt] = kg; }
                    }
                }
            }
        }

        if (p < 7) __syncthreads();  // stage of p+1 landed; all done reading buf[p&1]
    }

    // combine 4 quads per sample column (tie -> smaller k)
#pragma unroll
    for (int nt = 0; nt < NTN; ++nt) {
#pragma unroll
        for (int off = 16; off < 64; off <<= 1) {
            float ob = __shfl_xor(best[nt], off);
            int ok = __shfl_xor(bestk[nt], off);
            if (ob < best[nt] || (ob == best[nt] && ok < bestk[nt])) {
                best[nt] = ob;
                bestk[nt] = ok;
            }
        }
    }

    float contrib = 0.f;
    if (quad == 0) {
#pragma unroll
        for (int nt = 0; nt < NTN; ++nt) {
            if (srow[nt] < N_S) {
                labels[srow[nt]] = (float)bestk[nt];
                atomicAdd(&lhist[bestk[nt]], 1);
                contrib += fmaxf(xsqv[nt] + best[nt], 0.f);
            }
        }
    }
#pragma unroll
    for (int off = 32; off > 0; off >>= 1) contrib += __shfl_down(contrib, off);
    if (l == 0) red[w] = contrib;
    __syncthreads();
    if (t == 0) atomicAdd(inertia, red[0] + red[1] + red[2] + red[3]);

    for (int i = t; i < N_K; i += 256) {
        int v = lhist[i];
        if (v) atomicAdd(&ihist[i], v);
    }
}

// ---------------------------------------------------------------------------
// scatter (per iter): block-aggregated counting-sort scatter, 4 samples/thread.
// Each block redundantly computes the exclusive prefix of ihist in LDS.
// order entries are PACKED: (row << 9) | cluster  (row < 400000 -> fits int).
// ---------------------------------------------------------------------------
__global__ __launch_bounds__(256) void scatter_kernel(const float* __restrict__ labels,
                                                      const int* __restrict__ ihist,
                                                      int* __restrict__ cursor,
                                                      int* __restrict__ order) {
    __shared__ int lhist[N_K];
    __shared__ int excl[N_K];
    __shared__ int lbase[N_K];
    __shared__ int wtot[4];
    int t = threadIdx.x;
    long long i0 = (long long)blockIdx.x * 1024 + (long long)t * 4;

    for (int j = t; j < N_K; j += 256) lhist[j] = 0;

    // exclusive prefix of ihist[512] with 256 threads (2 entries each)
    int v0 = ihist[2 * t], v1 = ihist[2 * t + 1];
    int s = v0 + v1;
    int x = s;
    int lane = t & 63, w = t >> 6;
#pragma unroll
    for (int off = 1; off < 64; off <<= 1) {
        int y = __shfl_up(x, off);
        if (lane >= off) x += y;
    }
    if (lane == 63) wtot[w] = x;
    __syncthreads();  // lhist zeroed + wtot ready
    int woff = 0;
    for (int ww = 0; ww < w; ++ww) woff += wtot[ww];
    int ex = woff + x - s;
    excl[2 * t] = ex;
    excl[2 * t + 1] = ex + v0;

    int k0 = 0, k1 = 0, k2 = 0, k3 = 0, r0 = 0, r1 = 0, r2 = 0, r3 = 0;
    bool valid = (i0 < N_S);  // N_S % 4 == 0 -> whole quad valid or not
    if (valid) {
        float4 lab = *(const float4*)(labels + i0);
        k0 = (int)lab.x; k1 = (int)lab.y; k2 = (int)lab.z; k3 = (int)lab.w;
        r0 = atomicAdd(&lhist[k0], 1);
        r1 = atomicAdd(&lhist[k1], 1);
        r2 = atomicAdd(&lhist[k2], 1);
        r3 = atomicAdd(&lhist[k3], 1);
    }
    __syncthreads();  // lhist final + excl written
    for (int j = t; j < N_K; j += 256) {
        int c = lhist[j];
        lbase[j] = c ? (excl[j] + atomicAdd(&cursor[j], c)) : 0;
    }
    __syncthreads();
    if (valid) {
        int i = (int)i0;
        order[lbase[k0] + r0] = ((i + 0) << 9) | k0;
        order[lbase[k1] + r1] = ((i + 1) << 9) | k1;
        order[lbase[k2] + r2] = ((i + 2) << 9) | k2;
        order[lbase[k3] + r3] = ((i + 3) << 9) | k3;
    }
}

// ---------------------------------------------------------------------------
// csum (per iter): balanced 256-row windows over packed order[] (NO skew).
// 8 groups x 32 rows, 32 dim-threads x float4, unroll-8 independent loads.
// Fast path (P~0.67): whole window is one cluster -> 8 group-partials merge
// through part[8][128] LDS, ONE atomic per dim per block (128).
// Slow path: round-4-style per-segment flush. ~0.7M atomics total.
// Branch is block-uniform (ord_s[0] vs ord_s[nvalid-1]).
// ---------------------------------------------------------------------------
#define RPB 256

__device__ inline void flush4(float* __restrict__ sums, int k, int dbase, float4 acc) {
    float* sp = sums + k * N_F + dbase;
    atomicAdd(sp + 0, acc.x);
    atomicAdd(sp + 1, acc.y);
    atomicAdd(sp + 2, acc.z);
    atomicAdd(sp + 3, acc.w);
}

__global__ __launch_bounds__(256) void csum_kernel(const float* __restrict__ X,
                                                   const int* __restrict__ order,
                                                   float* __restrict__ sums) {
    __shared__ int ord_s[RPB];
    __shared__ float part[8][N_F];
    int t = threadIdx.x;
    int r0 = blockIdx.x * RPB;
    int nvalid = min(RPB, N_S - r0);  // last block: 128
    if (t < nvalid) ord_s[t] = order[r0 + t];
    __syncthreads();

    int g = t >> 5;              // 8 groups of up to 32 rows
    int dbase = (t & 31) << 2;   // 4 dims per thread (float4)
    const float* Xd = X + dbase;
    int base = g * 32;
    int gend = min(base + 32, nvalid);

    int kfirst = ord_s[0] & 511;
    int klast = ord_s[nvalid - 1] & 511;

    if (kfirst == klast) {
        // fast path: whole window one cluster -> LDS merge, 1 atomic/dim/block
        float4 acc = {0.f, 0.f, 0.f, 0.f};
#pragma unroll 8
        for (int i = base; i < gend; ++i) {
            int row = ord_s[i] >> 9;
            const float4 v = *(const float4*)(Xd + (long long)row * N_F);
            acc.x += v.x; acc.y += v.y; acc.z += v.z; acc.w += v.w;
        }
        *(float4*)&part[g][dbase] = acc;
        __syncthreads();
        if (t < N_F) {
            float r = 0.f;
#pragma unroll
            for (int gg = 0; gg < 8; ++gg) r += part[gg][t];
            atomicAdd(&sums[kfirst * N_F + t], r);
        }
    } else {
        // slow path: per-group segment flush (order is k-monotone)
        float4 acc = {0.f, 0.f, 0.f, 0.f};
        int kcur = (base < gend) ? (ord_s[base] & 511) : -1;
        for (int i = base; i < gend; ++i) {
            int e = ord_s[i];
            int k = e & 511;
            if (k != kcur) {
                flush4(sums, kcur, dbase, acc);
                acc = (float4){0.f, 0.f, 0.f, 0.f};
                kcur = k;
            }
            const float4 v = *(const float4*)(Xd + (long long)(e >> 9) * N_F);
            acc.x += v.x; acc.y += v.y; acc.z += v.z; acc.w += v.w;
        }
        if (kcur >= 0) flush4(sums, kcur, dbase, acc);
    }
}

// ---------------------------------------------------------------------------
// final update: cent = ihist>0 ? sums/ihist : cent
// ---------------------------------------------------------------------------
__global__ __launch_bounds__(128) void update_kernel(const float* __restrict__ sums,
                                                     const int* __restrict__ ihist,
                                                     float* __restrict__ cent) {
    int k = blockIdx.x;
    int d = threadIdx.x;
    float c = (float)ihist[k];
    float s = sums[k * N_F + d];
    float old = cent[k * N_F + d];
    cent[k * N_F + d] = (c > 0.f) ? (s / c) : old;
}

extern "C" void kernel_launch(void* const* d_in, const int* in_sizes, int n_in,
                              void* d_out, int out_size, void* d_ws, size_t ws_size,
                              hipStream_t stream) {
    const float* X = (const float*)d_in[0];
    const float* initc = (const float*)d_in[1];

    float* out = (float*)d_out;
    float* cent = out;                // [512*128] (output 0)
    float* labels = out + N_K * N_F;  // [400000]  (output 1)
    float* inertia = labels + N_S;    // [1]       (output 2)

    float* c_sq = (float*)d_ws;                           // 512 f
    float* sums = c_sq + N_K;                             // 512*128 f
    unsigned short* swhi = (unsigned short*)(sums + N_K * N_F);  // 65536 ush
    int* ihist = (int*)(swhi + N_K * N_F);                // 512 i
    int* cursor = ihist + N_K;                            // 512 i
    int* order = cursor + N_K;                            // 400000 i (packed row<<9|k)

    for (int it = 0; it < ITERS; ++it) {
        prep_update_kernel<<<N_K, 64, 0, stream>>>(initc, cent, sums, ihist, c_sq,
                                                   swhi, cursor, inertia, it > 0);
        assign_kernel<<<(N_S + 255) / 256, 256, 0, stream>>>(X, swhi, c_sq,
                                                             labels, inertia, ihist);
        scatter_kernel<<<(N_S + 1023) / 1024, 256, 0, stream>>>(labels, ihist, cursor,
                                                                order);
        csum_kernel<<<(N_S + RPB - 1) / RPB, 256, 0, stream>>>(X, order, sums);
    }
    update_kernel<<<N_K, N_F, 0, stream>>>(sums, ihist, cent);
}

// Round 10
// 1783.600 us; speedup vs baseline: 1.4992x; 1.2329x over previous
//
#include <hip/hip_runtime.h>

#define N_S 400000
#define N_F 128
#define N_K 512
#define ITERS 10

typedef __attribute__((ext_vector_type(8))) short short8;
typedef __attribute__((ext_vector_type(4))) float floatx4;

__device__ inline unsigned short f2bf(float f) {
    unsigned int u = __float_as_uint(f);
    unsigned int r = (u + 0x7FFFu + ((u >> 16) & 1u)) >> 16;
    return (unsigned short)r;
}

// v_cvt_pk_bf16_f32: lo16=cvt(lo), hi16=cvt(hi), RNE (same rounding as f2bf)
__device__ inline unsigned int cvt_pk_bf16(float lo, float hi) {
    unsigned int r;
    asm("v_cvt_pk_bf16_f32 %0, %1, %2" : "=v"(r) : "v"(lo), "v"(hi));
    return r;
}

// async global->LDS, 16B per lane, zero VGPR round-trip
__device__ inline void gload_lds16(const void* g, void* l) {
    __builtin_amdgcn_global_load_lds(
        (const __attribute__((address_space(1))) void*)g,
        (__attribute__((address_space(3))) void*)l, 16, 0, 0);
}

// Swizzled (MFMA-fragment-order) centroid storage, hi-only:
// cluster k, dim d -> frag ((k>>5)*8 + ((k>>4)&1)*4 + (d>>5)), lane quad*16+m, elem j
__device__ inline void put_sw(unsigned short* __restrict__ swhi, int k, int d, float v) {
    int c = k >> 5, mm = k & 31;
    int mt = mm >> 4, m = mm & 15;
    int kt = d >> 5, r = d & 31;
    int quad = r >> 3, j = r & 7;
    int lane = quad * 16 + m;
    int idx = ((c * 8 + mt * 4 + kt) * 64 + lane) * 8 + j;
    swhi[idx] = f2bf(v);
}

// ---------------------------------------------------------------------------
// prep_update (per iter): [optional] cent = ihist>0 ? sums/ihist : cent;
// write fp32 cent, c_sq, swizzled bf16 hi; zero sums/ihist/cursor/inertia.
// ---------------------------------------------------------------------------
__global__ __launch_bounds__(64) void prep_update_kernel(
    const float* __restrict__ src, float* __restrict__ cent,
    float* __restrict__ sums, int* __restrict__ ihist,
    float* __restrict__ c_sq, unsigned short* __restrict__ swhi,
    int* __restrict__ cursor, float* __restrict__ inertia, int do_update) {
    int k = blockIdx.x, lane = threadIdx.x;
    float a, b;
    float cnt = (float)ihist[k];  // prev-iter counts (garbage & unused when it==0)
    if (do_update) {
        float sa = sums[k * N_F + lane], sb = sums[k * N_F + 64 + lane];
        float olda = cent[k * N_F + lane], oldb = cent[k * N_F + 64 + lane];
        a = (cnt > 0.f) ? (sa / cnt) : olda;
        b = (cnt > 0.f) ? (sb / cnt) : oldb;
    } else {
        a = src[k * N_F + lane];
        b = src[k * N_F + 64 + lane];
    }
    cent[k * N_F + lane] = a;
    cent[k * N_F + 64 + lane] = b;
    sums[k * N_F + lane] = 0.f;
    sums[k * N_F + 64 + lane] = 0.f;
    put_sw(swhi, k, lane, a);
    put_sw(swhi, k, lane + 64, b);
    float s = fmaf(a, a, b * b);
#pragma unroll
    for (int off = 32; off > 0; off >>= 1) s += __shfl_down(s, off);
    if (lane == 0) {
        c_sq[k] = s;
        ihist[k] = 0;
        cursor[k] = 0;
        if (k == 0) *inertia = 0.f;
    }
}

// ---------------------------------------------------------------------------
// assign: bf16 MFMA. A-table (128KB, fragment-ordered) double-buffered
// through LDS in 16KB eighths via global_load_lds (async DMA, zero VGPRs).
// 8 phases x 2 chunks; LDS 37KB/block -> 4 blocks/CU by LDS.
// __launch_bounds__(256,2): NO 128-VGPR cap (the (256,4) cap caused a
// ~107MB/dispatch scratch spill, rounds 5-9; round-4 evidence: at (256,2)
// the allocator picks ~92 VGPR, zero spill, and 92 still permits 4 blocks/CU).
// B = 64 samples/wave in regs. argmin on d2' = c_sq - 2*dot.
// ---------------------------------------------------------------------------
#define CHUNK 32
#define NTN 4  // n-tiles per wave (64 samples)

__global__ __launch_bounds__(256, 2) void assign_kernel(
    const float* __restrict__ X,
    const unsigned short* __restrict__ swhi,
    const float* __restrict__ c_sq,
    float* __restrict__ labels,
    float* __restrict__ inertia,
    int* __restrict__ ihist) {
    __shared__ __align__(16) short8 a_lds[2][2 * 8 * 64];  // 2 x 16KB eighths
    __shared__ __align__(16) float csq_s[N_K];
    __shared__ int lhist[N_K];
    __shared__ float red[4];

    int t = threadIdx.x;
    int w = t >> 6, l = t & 63;
    int quad = l >> 4, l15 = l & 15;
    long long S0 = (long long)blockIdx.x * 256;

    // kick off eighth-0 DMA first (overlaps with everything below)
    {
        const char* gq = (const char*)swhi + t * 16;
        char* lq = (char*)a_lds[0] + t * 16;
#pragma unroll
        for (int i = 0; i < 4; ++i) gload_lds16(gq + i * 4096, lq + i * 4096);
    }

    for (int i = t; i < N_K; i += 256) {
        lhist[i] = 0;
        csq_s[i] = c_sq[i];
    }

    // B fragments (bf16 hi) + in-register x_sq; tail rows clamped.
    short8 bhi[NTN][4];
    float xsqv[NTN];
    long long srow[NTN];
#pragma unroll
    for (int nt = 0; nt < NTN; ++nt) {
        long long s = S0 + w * 64 + nt * 16 + l15;
        srow[nt] = s;
        long long ss = (s < N_S) ? s : (N_S - 1);
        const float4* xp = (const float4*)(X + ss * N_F);
        float sq = 0.f;
#pragma unroll
        for (int kt = 0; kt < 4; ++kt) {
            float4 va = xp[kt * 8 + quad * 2];
            float4 vb = xp[kt * 8 + quad * 2 + 1];
            float f[8] = {va.x, va.y, va.z, va.w, vb.x, vb.y, vb.z, vb.w};
            short8 h;
            unsigned int* hw = (unsigned int*)&h;
            hw[0] = cvt_pk_bf16(f[0], f[1]);
            hw[1] = cvt_pk_bf16(f[2], f[3]);
            hw[2] = cvt_pk_bf16(f[4], f[5]);
            hw[3] = cvt_pk_bf16(f[6], f[7]);
#pragma unroll
            for (int j = 0; j < 8; ++j) sq = fmaf(f[j], f[j], sq);
            bhi[nt][kt] = h;
        }
        // combine the 4 quads' partial sums (same sample across quads)
        sq += __shfl_xor(sq, 16);
        sq += __shfl_xor(sq, 32);
        xsqv[nt] = sq;
    }

    __syncthreads();  // drains vmcnt (p0 DMA + X loads), csq_s/lhist ready

    float best[NTN];
    int bestk[NTN];
#pragma unroll
    for (int nt = 0; nt < NTN; ++nt) { best[nt] = 3.4e38f; bestk[nt] = 0; }

#pragma unroll
    for (int p = 0; p < 8; ++p) {
        // issue next eighth's DMA (async; hidden under this phase's compute)
        if (p < 7) {
            const char* gq = (const char*)swhi + (p + 1) * 16384 + t * 16;
            char* lq = (char*)a_lds[(p + 1) & 1] + t * 16;
#pragma unroll
            for (int i = 0; i < 4; ++i) gload_lds16(gq + i * 4096, lq + i * 4096);
        }

        const short8* abase = a_lds[p & 1] + l;
#pragma unroll
        for (int cc = 0; cc < 2; ++cc) {
            int c = p * 2 + cc;
            floatx4 acc[2][NTN];
#pragma unroll
            for (int mt = 0; mt < 2; ++mt)
#pragma unroll
                for (int nt = 0; nt < NTN; ++nt) acc[mt][nt] = (floatx4){0.f, 0.f, 0.f, 0.f};

#pragma unroll
            for (int kt = 0; kt < 4; ++kt) {
                short8 a0 = abase[(cc * 8 + kt) * 64];
                short8 a1 = abase[(cc * 8 + 4 + kt) * 64];
#pragma unroll
                for (int nt = 0; nt < NTN; ++nt) {
                    acc[0][nt] = __builtin_amdgcn_mfma_f32_16x16x32_bf16(a0, bhi[nt][kt], acc[0][nt], 0, 0, 0);
                    acc[1][nt] = __builtin_amdgcn_mfma_f32_16x16x32_bf16(a1, bhi[nt][kt], acc[1][nt], 0, 0, 0);
                }
            }

#pragma unroll
            for (int mt = 0; mt < 2; ++mt) {
                float4 cs = ((const float4*)csq_s)[c * 8 + mt * 4 + quad];
#pragma unroll
                for (int r = 0; r < 4; ++r) {
                    float csr = (r == 0) ? cs.x : (r == 1) ? cs.y : (r == 2) ? cs.z : cs.w;
                    int kg = c * CHUNK + mt * 16 + quad * 4 + r;
#pragma unroll
                    for (int nt = 0; nt < NTN; ++nt) {
                        float d2 = fmaf(-2.f, acc[mt][nt][r], csr);
                        if (d2 < best[nt]) { best[nt] = d2; bestk[nt] = kg; }
                    }
                }
            }
        }

        if (p < 7) __syncthreads();  // stage of p+1 landed; all done reading buf[p&1]
    }

    // combine 4 quads per sample column (tie -> smaller k)
#pragma unroll
    for (int nt = 0; nt < NTN; ++nt) {
#pragma unroll
        for (int off = 16; off < 64; off <<= 1) {
            float ob = __shfl_xor(best[nt], off);
            int ok = __shfl_xor(bestk[nt], off);
            if (ob < best[nt] || (ob == best[nt] && ok < bestk[nt])) {
                best[nt] = ob;
                bestk[nt] = ok;
            }
        }
    }

    float contrib = 0.f;
    if (quad == 0) {
#pragma unroll
        for (int nt = 0; nt < NTN; ++nt) {
            if (srow[nt] < N_S) {
                labels[srow[nt]] = (float)bestk[nt];
                atomicAdd(&lhist[bestk[nt]], 1);
                contrib += fmaxf(xsqv[nt] + best[nt], 0.f);
            }
        }
    }
#pragma unroll
    for (int off = 32; off > 0; off >>= 1) contrib += __shfl_down(contrib, off);
    if (l == 0) red[w] = contrib;
    __syncthreads();
    if (t == 0) atomicAdd(inertia, red[0] + red[1] + red[2] + red[3]);

    for (int i = t; i < N_K; i += 256) {
        int v = lhist[i];
        if (v) atomicAdd(&ihist[i], v);
    }
}

// ---------------------------------------------------------------------------
// scatter (per iter): block-aggregated counting-sort scatter, 4 samples/thread.
// Each block redundantly computes the exclusive prefix of ihist in LDS.
// order entries are PACKED: (row << 9) | cluster  (row < 400000 -> fits int).
// ---------------------------------------------------------------------------
__global__ __launch_bounds__(256) void scatter_kernel(const float* __restrict__ labels,
                                                      const int* __restrict__ ihist,
                                                      int* __restrict__ cursor,
                                                      int* __restrict__ order) {
    __shared__ int lhist[N_K];
    __shared__ int excl[N_K];
    __shared__ int lbase[N_K];
    __shared__ int wtot[4];
    int t = threadIdx.x;
    long long i0 = (long long)blockIdx.x * 1024 + (long long)t * 4;

    for (int j = t; j < N_K; j += 256) lhist[j] = 0;

    // exclusive prefix of ihist[512] with 256 threads (2 entries each)
    int v0 = ihist[2 * t], v1 = ihist[2 * t + 1];
    int s = v0 + v1;
    int x = s;
    int lane = t & 63, w = t >> 6;
#pragma unroll
    for (int off = 1; off < 64; off <<= 1) {
        int y = __shfl_up(x, off);
        if (lane >= off) x += y;
    }
    if (lane == 63) wtot[w] = x;
    __syncthreads();  // lhist zeroed + wtot ready
    int woff = 0;
    for (int ww = 0; ww < w; ++ww) woff += wtot[ww];
    int ex = woff + x - s;
    excl[2 * t] = ex;
    excl[2 * t + 1] = ex + v0;

    int k0 = 0, k1 = 0, k2 = 0, k3 = 0, r0 = 0, r1 = 0, r2 = 0, r3 = 0;
    bool valid = (i0 < N_S);  // N_S % 4 == 0 -> whole quad valid or not
    if (valid) {
        float4 lab = *(const float4*)(labels + i0);
        k0 = (int)lab.x; k1 = (int)lab.y; k2 = (int)lab.z; k3 = (int)lab.w;
        r0 = atomicAdd(&lhist[k0], 1);
        r1 = atomicAdd(&lhist[k1], 1);
        r2 = atomicAdd(&lhist[k2], 1);
        r3 = atomicAdd(&lhist[k3], 1);
    }
    __syncthreads();  // lhist final + excl written
    for (int j = t; j < N_K; j += 256) {
        int c = lhist[j];
        lbase[j] = c ? (excl[j] + atomicAdd(&cursor[j], c)) : 0;
    }
    __syncthreads();
    if (valid) {
        int i = (int)i0;
        order[lbase[k0] + r0] = ((i + 0) << 9) | k0;
        order[lbase[k1] + r1] = ((i + 1) << 9) | k1;
        order[lbase[k2] + r2] = ((i + 2) << 9) | k2;
        order[lbase[k3] + r3] = ((i + 3) << 9) | k3;
    }
}

// ---------------------------------------------------------------------------
// csum (per iter): balanced 256-row windows over packed order[] (NO skew).
// 8 groups x 32 rows, 32 dim-threads x float4, unroll-8 independent loads.
// Fast path (P~0.67): whole window is one cluster -> 8 group-partials merge
// through part[8][128] LDS, ONE atomic per dim per block (128).
// Slow path: per-segment flush. Branch is block-uniform.
// ---------------------------------------------------------------------------
#define RPB 256

__device__ inline void flush4(float* __restrict__ sums, int k, int dbase, float4 acc) {
    float* sp = sums + k * N_F + dbase;
    atomicAdd(sp + 0, acc.x);
    atomicAdd(sp + 1, acc.y);
    atomicAdd(sp + 2, acc.z);
    atomicAdd(sp + 3, acc.w);
}

__global__ __launch_bounds__(256) void csum_kernel(const float* __restrict__ X,
                                                   const int* __restrict__ order,
                                                   float* __restrict__ sums) {
    __shared__ int ord_s[RPB];
    __shared__ float part[8][N_F];
    int t = threadIdx.x;
    int r0 = blockIdx.x * RPB;
    int nvalid = min(RPB, N_S - r0);  // last block: 128
    if (t < nvalid) ord_s[t] = order[r0 + t];
    __syncthreads();

    int g = t >> 5;              // 8 groups of up to 32 rows
    int dbase = (t & 31) << 2;   // 4 dims per thread (float4)
    const float* Xd = X + dbase;
    int base = g * 32;
    int gend = min(base + 32, nvalid);

    int kfirst = ord_s[0] & 511;
    int klast = ord_s[nvalid - 1] & 511;

    if (kfirst == klast) {
        // fast path: whole window one cluster -> LDS merge, 1 atomic/dim/block
        float4 acc = {0.f, 0.f, 0.f, 0.f};
#pragma unroll 8
        for (int i = base; i < gend; ++i) {
            int row = ord_s[i] >> 9;
            const float4 v = *(const float4*)(Xd + (long long)row * N_F);
            acc.x += v.x; acc.y += v.y; acc.z += v.z; acc.w += v.w;
        }
        *(float4*)&part[g][dbase] = acc;
        __syncthreads();
        if (t < N_F) {
            float r = 0.f;
#pragma unroll
            for (int gg = 0; gg < 8; ++gg) r += part[gg][t];
            atomicAdd(&sums[kfirst * N_F + t], r);
        }
    } else {
        // slow path: per-group segment flush (order is k-monotone)
        float4 acc = {0.f, 0.f, 0.f, 0.f};
        int kcur = (base < gend) ? (ord_s[base] & 511) : -1;
        for (int i = base; i < gend; ++i) {
            int e = ord_s[i];
            int k = e & 511;
            if (k != kcur) {
                flush4(sums, kcur, dbase, acc);
                acc = (float4){0.f, 0.f, 0.f, 0.f};
                kcur = k;
            }
            const float4 v = *(const float4*)(Xd + (long long)(e >> 9) * N_F);
            acc.x += v.x; acc.y += v.y; acc.z += v.z; acc.w += v.w;
        }
        if (kcur >= 0) flush4(sums, kcur, dbase, acc);
    }
}

// ---------------------------------------------------------------------------
// final update: cent = ihist>0 ? sums/ihist : cent
// ---------------------------------------------------------------------------
__global__ __launch_bounds__(128) void update_kernel(const float* __restrict__ sums,
                                                     const int* __restrict__ ihist,
                                                     float* __restrict__ cent) {
    int k = blockIdx.x;
    int d = threadIdx.x;
    float c = (float)ihist[k];
    float s = sums[k * N_F + d];
    float old = cent[k * N_F + d];
    cent[k * N_F + d] = (c > 0.f) ? (s / c) : old;
}

extern "C" void kernel_launch(void* const* d_in, const int* in_sizes, int n_in,
                              void* d_out, int out_size, void* d_ws, size_t ws_size,
                              hipStream_t stream) {
    const float* X = (const float*)d_in[0];
    const float* initc = (const float*)d_in[1];

    float* out = (float*)d_out;
    float* cent = out;                // [512*128] (output 0)
    float* labels = out + N_K * N_F;  // [400000]  (output 1)
    float* inertia = labels + N_S;    // [1]       (output 2)

    float* c_sq = (float*)d_ws;                           // 512 f
    float* sums = c_sq + N_K;                             // 512*128 f
    unsigned short* swhi = (unsigned short*)(sums + N_K * N_F);  // 65536 ush
    int* ihist = (int*)(swhi + N_K * N_F);                // 512 i
    int* cursor = ihist + N_K;                            // 512 i
    int* order = cursor + N_K;                            // 400000 i (packed row<<9|k)

    for (int it = 0; it < ITERS; ++it) {
        prep_update_kernel<<<N_K, 64, 0, stream>>>(initc, cent, sums, ihist, c_sq,
                                                   swhi, cursor, inertia, it > 0);
        assign_kernel<<<(N_S + 255) / 256, 256, 0, stream>>>(X, swhi, c_sq,
                                                             labels, inertia, ihist);
        scatter_kernel<<<(N_S + 1023) / 1024, 256, 0, stream>>>(labels, ihist, cursor,
                                                                order);
        csum_kernel<<<(N_S + RPB - 1) / RPB, 256, 0, stream>>>(X, order, sums);
    }
    update_kernel<<<N_K, N_F, 0, stream>>>(sums, ihist, cent);
}

// Round 11
// 1534.644 us; speedup vs baseline: 1.7425x; 1.1622x over previous
//
#include <hip/hip_runtime.h>

#define N_S 400000
#define N_F 128
#define N_K 512
#define ITERS 10

typedef __attribute__((ext_vector_type(8))) short short8;
typedef __attribute__((ext_vector_type(4))) float floatx4;

__device__ inline unsigned short f2bf(float f) {
    unsigned int u = __float_as_uint(f);
    unsigned int r = (u + 0x7FFFu + ((u >> 16) & 1u)) >> 16;
    return (unsigned short)r;
}

// v_cvt_pk_bf16_f32: lo16=cvt(lo), hi16=cvt(hi), RNE (same rounding as f2bf)
__device__ inline unsigned int cvt_pk_bf16(float lo, float hi) {
    unsigned int r;
    asm("v_cvt_pk_bf16_f32 %0, %1, %2" : "=v"(r) : "v"(lo), "v"(hi));
    return r;
}

// async global->LDS, 16B per lane, zero VGPR round-trip
__device__ inline void gload_lds16(const void* g, void* l) {
    __builtin_amdgcn_global_load_lds(
        (const __attribute__((address_space(1))) void*)g,
        (__attribute__((address_space(3))) void*)l, 16, 0, 0);
}

// Swizzled (MFMA-fragment-order) centroid storage, hi-only:
// cluster k, dim d -> frag ((k>>5)*8 + ((k>>4)&1)*4 + (d>>5)), lane quad*16+m, elem j
__device__ inline void put_sw(unsigned short* __restrict__ swhi, int k, int d, float v) {
    int c = k >> 5, mm = k & 31;
    int mt = mm >> 4, m = mm & 15;
    int kt = d >> 5, r = d & 31;
    int quad = r >> 3, j = r & 7;
    int lane = quad * 16 + m;
    int idx = ((c * 8 + mt * 4 + kt) * 64 + lane) * 8 + j;
    swhi[idx] = f2bf(v);
}

// ---------------------------------------------------------------------------
// prep_update (per iter): [optional] cent = ihist>0 ? sums/ihist : cent;
// write fp32 cent, c_sq, swizzled bf16 hi; zero sums/ihist/cursor/inertia.
// ---------------------------------------------------------------------------
__global__ __launch_bounds__(64) void prep_update_kernel(
    const float* __restrict__ src, float* __restrict__ cent,
    float* __restrict__ sums, int* __restrict__ ihist,
    float* __restrict__ c_sq, unsigned short* __restrict__ swhi,
    int* __restrict__ cursor, float* __restrict__ inertia, int do_update) {
    int k = blockIdx.x, lane = threadIdx.x;
    float a, b;
    float cnt = (float)ihist[k];  // prev-iter counts (garbage & unused when it==0)
    if (do_update) {
        float sa = sums[k * N_F + lane], sb = sums[k * N_F + 64 + lane];
        float olda = cent[k * N_F + lane], oldb = cent[k * N_F + 64 + lane];
        a = (cnt > 0.f) ? (sa / cnt) : olda;
        b = (cnt > 0.f) ? (sb / cnt) : oldb;
    } else {
        a = src[k * N_F + lane];
        b = src[k * N_F + 64 + lane];
    }
    cent[k * N_F + lane] = a;
    cent[k * N_F + 64 + lane] = b;
    sums[k * N_F + lane] = 0.f;
    sums[k * N_F + 64 + lane] = 0.f;
    put_sw(swhi, k, lane, a);
    put_sw(swhi, k, lane + 64, b);
    float s = fmaf(a, a, b * b);
#pragma unroll
    for (int off = 32; off > 0; off >>= 1) s += __shfl_down(s, off);
    if (lane == 0) {
        c_sq[k] = s;
        ihist[k] = 0;
        cursor[k] = 0;
        if (k == 0) *inertia = 0.f;
    }
}

// ---------------------------------------------------------------------------
// assign: bf16 MFMA, WHOLE A-table (128KB, fragment-ordered) resident in LDS.
// 512 threads (8 waves, 2/SIMD), 1 block/CU (133KB LDS), grid=256 blocks
// grid-striding over 782 tiles of 512 samples. ONE barrier per block (after
// the one-time table DMA); the tile loop is barrier-free -> waves free-run.
// Per tile per wave: X preamble (float4 + cvt_pk, in-reg ||x||^2) then
// 16 chunks of ds_read_b128 + MFMA (setprio-wrapped) + argmin epilogue.
// argmin on d2' = c_sq - 2*dot.
// ---------------------------------------------------------------------------
#define CHUNK 32
#define NTN 4     // n-tiles per wave (64 samples)
#define TILE 512  // samples per block-tile (8 waves x 64)
#define NTILES ((N_S + TILE - 1) / TILE)  // 782
#define AGRID 256

__global__ __launch_bounds__(512, 1) void assign_kernel(
    const float* __restrict__ X,
    const unsigned short* __restrict__ swhi,
    const float* __restrict__ c_sq,
    float* __restrict__ labels,
    float* __restrict__ inertia,
    int* __restrict__ ihist) {
    __shared__ __align__(16) short8 a_lds[16 * 8 * 64];  // full 128KB table
    __shared__ __align__(16) float csq_s[N_K];
    __shared__ int lhist[N_K];
    __shared__ float red[8];

    int t = threadIdx.x;
    int w = t >> 6, l = t & 63;
    int quad = l >> 4, l15 = l & 15;

    // one-time DMA of the whole table: 512 threads x 16B x 16 rounds = 128KB
    {
        const char* gq = (const char*)swhi + t * 16;
        char* lq = (char*)a_lds + t * 16;
#pragma unroll
        for (int i = 0; i < 16; ++i) gload_lds16(gq + i * 8192, lq + i * 8192);
    }

    for (int i = t; i < N_K; i += 512) {
        lhist[i] = 0;
        csq_s[i] = c_sq[i];
    }

    __syncthreads();  // drains vmcnt (table DMA); csq_s/lhist ready

    const short8* abase = a_lds + l;
    float inert = 0.f;

    for (int tile = blockIdx.x; tile < NTILES; tile += AGRID) {
        long long S0 = (long long)tile * TILE + w * 64;

        // B fragments (bf16 hi) + in-register x_sq; tail rows clamped.
        short8 bhi[NTN][4];
        float xsqv[NTN];
        long long srow[NTN];
#pragma unroll
        for (int nt = 0; nt < NTN; ++nt) {
            long long s = S0 + nt * 16 + l15;
            srow[nt] = s;
            long long ss = (s < N_S) ? s : (N_S - 1);
            const float4* xp = (const float4*)(X + ss * N_F);
            float sq = 0.f;
#pragma unroll
            for (int kt = 0; kt < 4; ++kt) {
                float4 va = xp[kt * 8 + quad * 2];
                float4 vb = xp[kt * 8 + quad * 2 + 1];
                float f[8] = {va.x, va.y, va.z, va.w, vb.x, vb.y, vb.z, vb.w};
                short8 h;
                unsigned int* hw = (unsigned int*)&h;
                hw[0] = cvt_pk_bf16(f[0], f[1]);
                hw[1] = cvt_pk_bf16(f[2], f[3]);
                hw[2] = cvt_pk_bf16(f[4], f[5]);
                hw[3] = cvt_pk_bf16(f[6], f[7]);
#pragma unroll
                for (int j = 0; j < 8; ++j) sq = fmaf(f[j], f[j], sq);
                bhi[nt][kt] = h;
            }
            // combine the 4 quads' partial sums (same sample across quads)
            sq += __shfl_xor(sq, 16);
            sq += __shfl_xor(sq, 32);
            xsqv[nt] = sq;
        }

        float best[NTN];
        int bestk[NTN];
#pragma unroll
        for (int nt = 0; nt < NTN; ++nt) { best[nt] = 3.4e38f; bestk[nt] = 0; }

#pragma unroll 4
        for (int c = 0; c < 16; ++c) {
            floatx4 acc[2][NTN];
#pragma unroll
            for (int mt = 0; mt < 2; ++mt)
#pragma unroll
                for (int nt = 0; nt < NTN; ++nt) acc[mt][nt] = (floatx4){0.f, 0.f, 0.f, 0.f};

            __builtin_amdgcn_s_setprio(1);
#pragma unroll
            for (int kt = 0; kt < 4; ++kt) {
                short8 a0 = abase[(c * 8 + kt) * 64];
                short8 a1 = abase[(c * 8 + 4 + kt) * 64];
#pragma unroll
                for (int nt = 0; nt < NTN; ++nt) {
                    acc[0][nt] = __builtin_amdgcn_mfma_f32_16x16x32_bf16(a0, bhi[nt][kt], acc[0][nt], 0, 0, 0);
                    acc[1][nt] = __builtin_amdgcn_mfma_f32_16x16x32_bf16(a1, bhi[nt][kt], acc[1][nt], 0, 0, 0);
                }
            }
            __builtin_amdgcn_s_setprio(0);

#pragma unroll
            for (int mt = 0; mt < 2; ++mt) {
                float4 cs = ((const float4*)csq_s)[c * 8 + mt * 4 + quad];
#pragma unroll
                for (int r = 0; r < 4; ++r) {
                    float csr = (r == 0) ? cs.x : (r == 1) ? cs.y : (r == 2) ? cs.z : cs.w;
                    int kg = c * CHUNK + mt * 16 + quad * 4 + r;
#pragma unroll
                    for (int nt = 0; nt < NTN; ++nt) {
                        float d2 = fmaf(-2.f, acc[mt][nt][r], csr);
                        if (d2 < best[nt]) { best[nt] = d2; bestk[nt] = kg; }
                    }
                }
            }
        }

        // combine 4 quads per sample column (tie -> smaller k)
#pragma unroll
        for (int nt = 0; nt < NTN; ++nt) {
#pragma unroll
            for (int off = 16; off < 64; off <<= 1) {
                float ob = __shfl_xor(best[nt], off);
                int ok = __shfl_xor(bestk[nt], off);
                if (ob < best[nt] || (ob == best[nt] && ok < bestk[nt])) {
                    best[nt] = ob;
                    bestk[nt] = ok;
                }
            }
        }

        if (quad == 0) {
#pragma unroll
            for (int nt = 0; nt < NTN; ++nt) {
                if (srow[nt] < N_S) {
                    labels[srow[nt]] = (float)bestk[nt];
                    atomicAdd(&lhist[bestk[nt]], 1);
                    inert += fmaxf(xsqv[nt] + best[nt], 0.f);
                }
            }
        }
    }

    // block-level inertia reduce + lhist flush
#pragma unroll
    for (int off = 32; off > 0; off >>= 1) inert += __shfl_down(inert, off);
    if (l == 0) red[w] = inert;
    __syncthreads();
    if (t == 0) {
        float s = 0.f;
#pragma unroll
        for (int i = 0; i < 8; ++i) s += red[i];
        atomicAdd(inertia, s);
    }
    for (int i = t; i < N_K; i += 512) {
        int v = lhist[i];
        if (v) atomicAdd(&ihist[i], v);
    }
}

// ---------------------------------------------------------------------------
// scatter (per iter): block-aggregated counting-sort scatter, 4 samples/thread.
// Each block redundantly computes the exclusive prefix of ihist in LDS.
// order entries are PACKED: (row << 9) | cluster  (row < 400000 -> fits int).
// ---------------------------------------------------------------------------
__global__ __launch_bounds__(256) void scatter_kernel(const float* __restrict__ labels,
                                                      const int* __restrict__ ihist,
                                                      int* __restrict__ cursor,
                                                      int* __restrict__ order) {
    __shared__ int lhist[N_K];
    __shared__ int excl[N_K];
    __shared__ int lbase[N_K];
    __shared__ int wtot[4];
    int t = threadIdx.x;
    long long i0 = (long long)blockIdx.x * 1024 + (long long)t * 4;

    for (int j = t; j < N_K; j += 256) lhist[j] = 0;

    // exclusive prefix of ihist[512] with 256 threads (2 entries each)
    int v0 = ihist[2 * t], v1 = ihist[2 * t + 1];
    int s = v0 + v1;
    int x = s;
    int lane = t & 63, w = t >> 6;
#pragma unroll
    for (int off = 1; off < 64; off <<= 1) {
        int y = __shfl_up(x, off);
        if (lane >= off) x += y;
    }
    if (lane == 63) wtot[w] = x;
    __syncthreads();  // lhist zeroed + wtot ready
    int woff = 0;
    for (int ww = 0; ww < w; ++ww) woff += wtot[ww];
    int ex = woff + x - s;
    excl[2 * t] = ex;
    excl[2 * t + 1] = ex + v0;

    int k0 = 0, k1 = 0, k2 = 0, k3 = 0, r0 = 0, r1 = 0, r2 = 0, r3 = 0;
    bool valid = (i0 < N_S);  // N_S % 4 == 0 -> whole quad valid or not
    if (valid) {
        float4 lab = *(const float4*)(labels + i0);
        k0 = (int)lab.x; k1 = (int)lab.y; k2 = (int)lab.z; k3 = (int)lab.w;
        r0 = atomicAdd(&lhist[k0], 1);
        r1 = atomicAdd(&lhist[k1], 1);
        r2 = atomicAdd(&lhist[k2], 1);
        r3 = atomicAdd(&lhist[k3], 1);
    }
    __syncthreads();  // lhist final + excl written
    for (int j = t; j < N_K; j += 256) {
        int c = lhist[j];
        lbase[j] = c ? (excl[j] + atomicAdd(&cursor[j], c)) : 0;
    }
    __syncthreads();
    if (valid) {
        int i = (int)i0;
        order[lbase[k0] + r0] = ((i + 0) << 9) | k0;
        order[lbase[k1] + r1] = ((i + 1) << 9) | k1;
        order[lbase[k2] + r2] = ((i + 2) << 9) | k2;
        order[lbase[k3] + r3] = ((i + 3) << 9) | k3;
    }
}

// ---------------------------------------------------------------------------
// csum (per iter): balanced 256-row windows over packed order[] (NO skew).
// 8 groups x 32 rows, 32 dim-threads x float4, unroll-8 independent loads.
// Fast path (P~0.67): whole window is one cluster -> 8 group-partials merge
// through part[8][128] LDS, ONE atomic per dim per block (128).
// Slow path: per-segment flush. Branch is block-uniform.
// ---------------------------------------------------------------------------
#define RPB 256

__device__ inline void flush4(float* __restrict__ sums, int k, int dbase, float4 acc) {
    float* sp = sums + k * N_F + dbase;
    atomicAdd(sp + 0, acc.x);
    atomicAdd(sp + 1, acc.y);
    atomicAdd(sp + 2, acc.z);
    atomicAdd(sp + 3, acc.w);
}

__global__ __launch_bounds__(256) void csum_kernel(const float* __restrict__ X,
                                                   const int* __restrict__ order,
                                                   float* __restrict__ sums) {
    __shared__ int ord_s[RPB];
    __shared__ float part[8][N_F];
    int t = threadIdx.x;
    int r0 = blockIdx.x * RPB;
    int nvalid = min(RPB, N_S - r0);  // last block: 128
    if (t < nvalid) ord_s[t] = order[r0 + t];
    __syncthreads();

    int g = t >> 5;              // 8 groups of up to 32 rows
    int dbase = (t & 31) << 2;   // 4 dims per thread (float4)
    const float* Xd = X + dbase;
    int base = g * 32;
    int gend = min(base + 32, nvalid);

    int kfirst = ord_s[0] & 511;
    int klast = ord_s[nvalid - 1] & 511;

    if (kfirst == klast) {
        // fast path: whole window one cluster -> LDS merge, 1 atomic/dim/block
        float4 acc = {0.f, 0.f, 0.f, 0.f};
#pragma unroll 8
        for (int i = base; i < gend; ++i) {
            int row = ord_s[i] >> 9;
            const float4 v = *(const float4*)(Xd + (long long)row * N_F);
            acc.x += v.x; acc.y += v.y; acc.z += v.z; acc.w += v.w;
        }
        *(float4*)&part[g][dbase] = acc;
        __syncthreads();
        if (t < N_F) {
            float r = 0.f;
#pragma unroll
            for (int gg = 0; gg < 8; ++gg) r += part[gg][t];
            atomicAdd(&sums[kfirst * N_F + t], r);
        }
    } else {
        // slow path: per-group segment flush (order is k-monotone)
        float4 acc = {0.f, 0.f, 0.f, 0.f};
        int kcur = (base < gend) ? (ord_s[base] & 511) : -1;
        for (int i = base; i < gend; ++i) {
            int e = ord_s[i];
            int k = e & 511;
            if (k != kcur) {
                flush4(sums, kcur, dbase, acc);
                acc = (float4){0.f, 0.f, 0.f, 0.f};
                kcur = k;
            }
            const float4 v = *(const float4*)(Xd + (long long)(e >> 9) * N_F);
            acc.x += v.x; acc.y += v.y; acc.z += v.z; acc.w += v.w;
        }
        if (kcur >= 0) flush4(sums, kcur, dbase, acc);
    }
}

// ---------------------------------------------------------------------------
// final update: cent = ihist>0 ? sums/ihist : cent
// ---------------------------------------------------------------------------
__global__ __launch_bounds__(128) void update_kernel(const float* __restrict__ sums,
                                                     const int* __restrict__ ihist,
                                                     float* __restrict__ cent) {
    int k = blockIdx.x;
    int d = threadIdx.x;
    float c = (float)ihist[k];
    float s = sums[k * N_F + d];
    float old = cent[k * N_F + d];
    cent[k * N_F + d] = (c > 0.f) ? (s / c) : old;
}

extern "C" void kernel_launch(void* const* d_in, const int* in_sizes, int n_in,
                              void* d_out, int out_size, void* d_ws, size_t ws_size,
                              hipStream_t stream) {
    const float* X = (const float*)d_in[0];
    const float* initc = (const float*)d_in[1];

    float* out = (float*)d_out;
    float* cent = out;                // [512*128] (output 0)
    float* labels = out + N_K * N_F;  // [400000]  (output 1)
    float* inertia = labels + N_S;    // [1]       (output 2)

    float* c_sq = (float*)d_ws;                           // 512 f
    float* sums = c_sq + N_K;                             // 512*128 f
    unsigned short* swhi = (unsigned short*)(sums + N_K * N_F);  // 65536 ush
    int* ihist = (int*)(swhi + N_K * N_F);                // 512 i
    int* cursor = ihist + N_K;                            // 512 i
    int* order = cursor + N_K;                            // 400000 i (packed row<<9|k)

    for (int it = 0; it < ITERS; ++it) {
        prep_update_kernel<<<N_K, 64, 0, stream>>>(initc, cent, sums, ihist, c_sq,
                                                   swhi, cursor, inertia, it > 0);
        assign_kernel<<<AGRID, 512, 0, stream>>>(X, swhi, c_sq,
                                                 labels, inertia, ihist);
        scatter_kernel<<<(N_S + 1023) / 1024, 256, 0, stream>>>(labels, ihist, cursor,
                                                                order);
        csum_kernel<<<(N_S + RPB - 1) / RPB, 256, 0, stream>>>(X, order, sums);
    }
    update_kernel<<<N_K, N_F, 0, stream>>>(sums, ihist, cent);
}